// Round 5
// baseline (991.016 us; speedup 1.0000x reference)
//
#include <hip/hip_runtime.h>
#include <hip/hip_bf16.h>
#include <float.h>
#include <math.h>

typedef __hip_bfloat16 bf16;

#define NEGBIG (-1e30f)

__device__ __forceinline__ float ldv(const bf16* p, int i) { return __bfloat162float(p[i]); }
__device__ __forceinline__ float ldv(const float* p, int i) { return p[i]; }
__device__ __forceinline__ void stv(float* p, int i, float v) { p[i] = v; }
__device__ __forceinline__ void stv(bf16* p, int i, float v) { p[i] = __float2bfloat16(v); }

__device__ __forceinline__ float wave_sum(float v) {
#pragma unroll
  for (int off = 32; off; off >>= 1) v += __shfl_xor(v, off, 64);
  return v;
}
__device__ __forceinline__ float wave_max(float v) {
#pragma unroll
  for (int off = 32; off; off >>= 1) v = fmaxf(v, __shfl_xor(v, off, 64));
  return v;
}

// ---------------- generic tiled GEMM: C(MxN) = A(MxK) @ B(KxN), f32 accum ----
template <typename TA, typename TB, typename TC>
__global__ __launch_bounds__(256) void gemm_tile(
    const TA* __restrict__ A, const TB* __restrict__ B, TC* __restrict__ C,
    int M, int N, int K, int lda, int ldb, int ldc)
{
  __shared__ float As[16][65];
  __shared__ float Bs[16][65];
  const int tid = threadIdx.x;
  const int tx = tid & 15, ty = tid >> 4;
  const int row0 = blockIdx.y * 64, col0 = blockIdx.x * 64;
  float acc[4][4] = {};
  for (int k0 = 0; k0 < K; k0 += 16) {
#pragma unroll
    for (int l = 0; l < 4; ++l) {
      int idx = tid + l * 256;
      int m = idx >> 4, kk = idx & 15;
      As[kk][m] = ldv(A, (row0 + m) * lda + k0 + kk);
      int kk2 = idx >> 6, n = idx & 63;
      Bs[kk2][n] = ldv(B, (k0 + kk2) * ldb + col0 + n);
    }
    __syncthreads();
#pragma unroll
    for (int kk = 0; kk < 16; ++kk) {
      float a[4], b[4];
#pragma unroll
      for (int i = 0; i < 4; ++i) a[i] = As[kk][ty * 4 + i];
#pragma unroll
      for (int j = 0; j < 4; ++j) b[j] = Bs[kk][tx * 4 + j];
#pragma unroll
      for (int i = 0; i < 4; ++i)
#pragma unroll
        for (int j = 0; j < 4; ++j) acc[i][j] += a[i] * b[j];
    }
    __syncthreads();
  }
#pragma unroll
  for (int i = 0; i < 4; ++i)
#pragma unroll
    for (int j = 0; j < 4; ++j)
      stv(C, (row0 + ty * 4 + i) * ldc + col0 + tx * 4 + j, acc[i][j]);
}

// ---------------- RoPE (first 32 dims) + RMSNorm, one wave per 64-dim row ----
__global__ __launch_bounds__(256) void rope_rms_kernel(
    float* __restrict__ x, const float* __restrict__ g, int rows, int posShift)
{
  const int lane = threadIdx.x & 63;
  const int wid = threadIdx.x >> 6;
  const int r = blockIdx.x * 4 + wid;
  if (r >= rows) return;
  const int pos = r >> posShift;
  float val = x[r * 64 + lane];
  float p = __shfl_xor(val, 16, 64);
  float out = val;
  if (lane < 32) {
    int i = lane & 15;
    double ang = (double)pos * pow(10000.0, -(double)i / 16.0);
    float cc = (float)cos(ang), ss = (float)sin(ang);
    out = (lane < 16) ? (val * cc - p * ss) : (p * ss + val * cc);
  }
  float ms = wave_sum(out * out) * (1.0f / 64.0f);
  float rn = rsqrtf(ms + 1e-6f);
  x[r * 64 + lane] = out * rn * ldv(g, lane);
}

// ---------------- block-mean compression: kc/vc (64 blocks x 64 dims) --------
__global__ void compress_kernel(const float* __restrict__ k, const float* __restrict__ v,
                                float* __restrict__ kc, float* __restrict__ vc)
{
  const int n = blockIdx.x;   // block index 0..63
  const int d = threadIdx.x;  // dim 0..63
  float sk = 0.f, sv = 0.f;
  for (int j = 0; j < 32; ++j) {
    sk += k[(n * 32 + j) * 64 + d];
    sv += v[(n * 32 + j) * 64 + d];
  }
  kc[n * 64 + d] = sk * (1.0f / 32.0f);
  vc[n * 64 + d] = sv * (1.0f / 32.0f);
}

// ---------------- attention: one wave per (qpos, head) -----------------------
__global__ __launch_bounds__(256) void attn_kernel(
    const float* __restrict__ q, const float* __restrict__ kbuf, const float* __restrict__ vbuf,
    const float* __restrict__ kc, const float* __restrict__ vc,
    const float* __restrict__ w_gate, const float* __restrict__ b_gate,
    const float* __restrict__ sink, float* __restrict__ mixed)
{
  __shared__ __align__(16) float shq[4][64];
  __shared__ float shp[4][64];
  __shared__ int shsel[4][16];
  const int lane = threadIdx.x & 63;
  const int wid = threadIdx.x >> 6;
  const int r = blockIdx.x * 4 + wid;   // r = qpos*8 + h
  const int qpos = r >> 3, h = r & 7;
  const float scale = 0.125f;

  float qv = q[r * 64 + lane];
  shq[wid][lane] = qv;

  // ---- gate: sigmoid(q @ w_gate + b_gate), normalized ----
  float z0 = qv * ldv(w_gate, lane * 3 + 0);
  float z1 = qv * ldv(w_gate, lane * 3 + 1);
  float z2 = qv * ldv(w_gate, lane * 3 + 2);
  z0 = wave_sum(z0) + ldv(b_gate, 0);
  z1 = wave_sum(z1) + ldv(b_gate, 1);
  z2 = wave_sum(z2) + ldv(b_gate, 2);
  float ga0 = 1.f / (1.f + expf(-z0));
  float ga1 = 1.f / (1.f + expf(-z1));
  float ga2 = 1.f / (1.f + expf(-z2));
  float gs = fmaxf(ga0 + ga1 + ga2, 1e-6f);
  float ginv = 1.f / gs;
  ga0 *= ginv; ga1 *= ginv; ga2 *= ginv;

  const float4* qr = reinterpret_cast<const float4*>(&shq[wid][0]);
  const float snk = ldv(sink, h);
  const int nv = (qpos + 1) >> 5;  // valid compressed blocks

  // ---- compressed scores (lane = block index) ----
  float dot = 0.f;
  {
    const float4* kr = reinterpret_cast<const float4*>(kc + lane * 64);
#pragma unroll
    for (int d4 = 0; d4 < 16; ++d4) {
      float4 a = qr[d4], b = kr[d4];
      dot += a.x * b.x + a.y * b.y + a.z * b.z + a.w * b.w;
    }
  }
  float sc = dot * scale;

  float comp_out = 0.f;
  if (nv > 0) {
    float scomp = (lane < nv) ? sc : NEGBIG;
    float m = fmaxf(wave_max(scomp), snk);
    float e = (lane < nv) ? expf(sc - m) : 0.f;
    float S = wave_sum(e) + expf(snk - m);
    shp[wid][lane] = e / S;
    float co = 0.f;
    for (int n = 0; n < nv; ++n) co += shp[wid][n] * vc[n * 64 + lane];
    comp_out = co;
  }

  // ---- top-16 block selection (emulates jax.lax.top_k tie semantics) ----
  {
    float selv = (lane < nv) ? sc : -FLT_MAX;   // invalid = -FLT_MAX (picked by index order)
#pragma unroll
    for (int it = 0; it < 16; ++it) {
      float bv = selv; int bi = lane;
#pragma unroll
      for (int off = 32; off; off >>= 1) {
        float ov = __shfl_xor(bv, off, 64);
        int oi = __shfl_xor(bi, off, 64);
        if (ov > bv || (ov == bv && oi < bi)) { bv = ov; bi = oi; }
      }
      if (lane == 0) shsel[wid][it] = bi;
      if (lane == bi) selv = -INFINITY;         // removed, never re-picked
    }
  }

  // ---- selected branch: 16 blocks x 32 tokens, 2 blocks per 64-lane chunk ----
  float M = NEGBIG, S = 0.f, osel = 0.f;
  for (int c = 0; c < 8; ++c) {
    int b0 = shsel[wid][2 * c], b1 = shsel[wid][2 * c + 1];
    int tok = ((lane < 32) ? b0 : b1) * 32 + (lane & 31);
    bool ok = (tok <= qpos);
    float s = NEGBIG;
    if (ok) {
      const float4* kr = reinterpret_cast<const float4*>(kbuf + tok * 64);
      float dd = 0.f;
#pragma unroll
      for (int d4 = 0; d4 < 16; ++d4) {
        float4 a = qr[d4], b = kr[d4];
        dd += a.x * b.x + a.y * b.y + a.z * b.z + a.w * b.w;
      }
      s = dd * scale;
    }
    float Mn = fmaxf(M, wave_max(s));
    float e = ok ? expf(s - Mn) : 0.f;
    float cs = wave_sum(e);
    float corr = expf(M - Mn);
    S = S * corr + cs;
    shp[wid][lane] = e;
    float acc = 0.f;
    int base0 = b0 * 32, base1 = b1 * 32;
    for (int l = 0; l < 32; ++l) acc += shp[wid][l] * vbuf[(base0 + l) * 64 + lane];
    for (int l = 0; l < 32; ++l) acc += shp[wid][32 + l] * vbuf[(base1 + l) * 64 + lane];
    osel = osel * corr + acc;
    M = Mn;
  }
  osel /= S;

  // ---- sliding-window branch (window 512, with sink) ----
  float Mw = NEGBIG, Sw = 0.f, osw = 0.f;
  int kstart = qpos - 511; if (kstart < 0) kstart = 0;
  int cnt = qpos - kstart + 1;
  int nch = (cnt + 63) >> 6;
  for (int c = 0; c < nch; ++c) {
    int tok = kstart + c * 64 + lane;
    bool ok = (tok <= qpos);
    float s = NEGBIG;
    if (ok) {
      const float4* kr = reinterpret_cast<const float4*>(kbuf + tok * 64);
      float dd = 0.f;
#pragma unroll
      for (int d4 = 0; d4 < 16; ++d4) {
        float4 a = qr[d4], b = kr[d4];
        dd += a.x * b.x + a.y * b.y + a.z * b.z + a.w * b.w;
      }
      s = dd * scale;
    }
    float Mn = fmaxf(Mw, wave_max(s));
    float e = ok ? expf(s - Mn) : 0.f;
    float cs = wave_sum(e);
    float corr = expf(Mw - Mn);
    Sw = Sw * corr + cs;
    shp[wid][lane] = e;
    float acc = 0.f;
    int base = kstart + c * 64;
    for (int l = 0; l < 64; ++l) acc += shp[wid][l] * vbuf[(base + l) * 64 + lane];
    osw = osw * corr + acc;
    Mw = Mn;
  }
  {
    float Mf = fmaxf(Mw, snk);
    float corr = expf(Mw - Mf);
    float Sf = Sw * corr + expf(snk - Mf);
    osw = osw * corr / Sf;
  }

  mixed[r * 64 + lane] = ga0 * comp_out + ga1 * osel + ga2 * osw;
}

// ---------------- launch ----------------
extern "C" void kernel_launch(void* const* d_in, const int* in_sizes, int n_in,
                              void* d_out, int out_size, void* d_ws, size_t ws_size,
                              hipStream_t stream) {
  const float* h      = (const float*)d_in[0];
  const float* w_qc   = (const float*)d_in[1];
  const float* w_qup  = (const float*)d_in[2];
  const float* w_k    = (const float*)d_in[3];
  const float* w_v    = (const float*)d_in[4];
  const float* g_qn   = (const float*)d_in[5];
  const float* g_kn   = (const float*)d_in[6];
  const float* w_gate = (const float*)d_in[7];
  const float* b_gate = (const float*)d_in[8];
  const float* sink   = (const float*)d_in[9];
  const float* wog    = (const float*)d_in[10];
  const float* w_out  = (const float*)d_in[11];
  float* out = (float*)d_out;

  float* ws = (float*)d_ws;
  float* hc = ws;                    // 2048*256
  float* qb = hc + 2048 * 256;       // 2048*512  (t, h, d)
  float* kb = qb + 2048 * 512;       // 2048*64
  float* vb = kb + 2048 * 64;        // 2048*64
  float* kc = vb + 2048 * 64;        // 64*64
  float* vc = kc + 64 * 64;          // 64*64
  float* mx = vc + 64 * 64;          // 2048*512  (t, h, d)
  float* y1 = mx + 2048 * 512;       // 2048*1024

  dim3 blk(256);
  // hc = h @ w_qc
  gemm_tile<float, float, float><<<dim3(4, 32), blk, 0, stream>>>(h, w_qc, hc, 2048, 256, 1024, 1024, 256, 256);
  // q_raw = hc @ w_qup
  gemm_tile<float, float, float><<<dim3(8, 32), blk, 0, stream>>>(hc, w_qup, qb, 2048, 512, 256, 256, 512, 512);
  // k_raw = h @ w_k ; v = h @ w_v
  gemm_tile<float, float, float><<<dim3(1, 32), blk, 0, stream>>>(h, w_k, kb, 2048, 64, 1024, 1024, 64, 64);
  gemm_tile<float, float, float><<<dim3(1, 32), blk, 0, stream>>>(h, w_v, vb, 2048, 64, 1024, 1024, 64, 64);
  // RoPE + RMSNorm
  rope_rms_kernel<<<dim3(4096), blk, 0, stream>>>(qb, g_qn, 16384, 3);
  rope_rms_kernel<<<dim3(512), blk, 0, stream>>>(kb, g_kn, 2048, 0);
  // compressed K/V
  compress_kernel<<<dim3(64), dim3(64), 0, stream>>>(kb, vb, kc, vc);
  // attention (comp + selected + sliding window + gate mix)
  attn_kernel<<<dim3(4096), blk, 0, stream>>>(qb, kb, vb, kc, vc, w_gate, b_gate, sink, mx);
  // grouped projection: y1[:, g*512:(g+1)*512] = mx[:, g*256:(g+1)*256] @ wog[g]
  gemm_tile<float, float, float><<<dim3(8, 32), blk, 0, stream>>>(mx, wog, y1, 2048, 512, 256, 512, 512, 1024);
  gemm_tile<float, float, float><<<dim3(8, 32), blk, 0, stream>>>(mx + 256, wog + 256 * 512, y1 + 512, 2048, 512, 256, 512, 512, 1024);
  // out = y1 @ w_out  (f32 store)
  gemm_tile<float, float, float><<<dim3(16, 32), blk, 0, stream>>>(y1, w_out, out, 2048, 1024, 1024, 1024, 1024, 1024);
}